// Round 1
// baseline (423.693 us; speedup 1.0000x reference)
//
#include <hip/hip_runtime.h>

typedef __attribute__((ext_vector_type(8))) short short8;
typedef __attribute__((ext_vector_type(4))) float f32x4;
typedef __attribute__((ext_vector_type(4))) float flt4;
typedef unsigned short bfbits;

#define DEVI __device__ __forceinline__

constexpr int Bc = 4, Sc = 2048, Dc = 1024, Hc = 16, HDc = 64;
constexpr int M1 = Bc * Sc;     // 8192
constexpr int N1 = 3 * Hc * HDc; // 3072
constexpr int Kd = Dc;          // 1024

typedef __attribute__((address_space(1))) const unsigned int gas_u32;
typedef __attribute__((address_space(3))) unsigned int las_u32;

DEVI void gld_lds16(const void* g, void* l) {
  __builtin_amdgcn_global_load_lds((gas_u32*)g, (las_u32*)l, 16, 0, 0);
}

DEVI unsigned short f2bf(float f) {
  unsigned int x = __builtin_bit_cast(unsigned int, f);
  x = x + 0x7fffu + ((x >> 16) & 1u);
  return (unsigned short)(x >> 16);
}

DEVI f32x4 zero4() { f32x4 z = {0.f, 0.f, 0.f, 0.f}; return z; }

DEVI short8 lds8(const void* base, int byteoff) {
  return *(const short8*)((const char*)base + byteoff);
}

// ---------------- cast x (fp32 -> bf16), 8 elems/thread ----------------
__global__ void cast_x_kernel(const float* __restrict__ in, bfbits* __restrict__ out, int n8) {
  int i = blockIdx.x * 256 + threadIdx.x;
  if (i >= n8) return;
  const flt4* p = (const flt4*)in;
  flt4 a = p[(size_t)2 * i];
  flt4 b = p[(size_t)2 * i + 1];
  short8 r;
  r[0] = (short)f2bf(a[0]); r[1] = (short)f2bf(a[1]);
  r[2] = (short)f2bf(a[2]); r[3] = (short)f2bf(a[3]);
  r[4] = (short)f2bf(b[0]); r[5] = (short)f2bf(b[1]);
  r[6] = (short)f2bf(b[2]); r[7] = (short)f2bf(b[3]);
  *(short8*)(out + (size_t)8 * i) = r;
}

// ---------------- transpose + cast: in[R][C] fp32 -> out[C][R] bf16 ----------------
__global__ void transpose_cast_kernel(const float* __restrict__ in, bfbits* __restrict__ out,
                                      int R, int C) {
  __shared__ float tile[32][33];
  int bc = blockIdx.x * 32, br = blockIdx.y * 32;
  int tx = threadIdx.x & 31, ty = threadIdx.x >> 5; // 32 x 8
#pragma unroll
  for (int i = 0; i < 32; i += 8)
    tile[ty + i][tx] = in[(size_t)(br + ty + i) * C + bc + tx];
  __syncthreads();
#pragma unroll
  for (int i = 0; i < 32; i += 8)
    out[(size_t)(bc + ty + i) * R + br + tx] = f2bf(tile[tx][ty + i]);
}

// ---------------- GEMM: C[M][N] = A[M][K] * Bt[N][K]^T + bias ----------------
// EPI 0: scatter bf16 into Q/K/V [BH][S][HD]   EPI 1: fp32 out[M][N]
template <int EPI>
__global__ __launch_bounds__(256, 2) void gemm_bt_kernel(
    const bfbits* __restrict__ A, const bfbits* __restrict__ Bt,
    const float* __restrict__ bias,
    bfbits* __restrict__ outQ, bfbits* __restrict__ outK, bfbits* __restrict__ outV,
    float* __restrict__ outF, int M, int N, int K) {
  __shared__ bfbits sA[128 * 64];
  __shared__ bfbits sB[128 * 64];
  const int t = threadIdx.x;
  const int wid = t >> 6, l = t & 63;
  const int lr = l & 15, lg = l >> 4;
  const int m0 = blockIdx.y * 128, n0 = blockIdx.x * 128;
  const int wr = (wid >> 1) * 64, wc = (wid & 1) * 64;

  f32x4 acc[4][4];
#pragma unroll
  for (int i = 0; i < 4; ++i)
#pragma unroll
    for (int j = 0; j < 4; ++j) acc[i][j] = zero4();

  const int row_s = t >> 3; // 0..31
  const int grp_s = t & 7;

  for (int kt = 0; kt < K; kt += 64) {
    // stage A,B tiles: linear LDS dest, inverse-swizzled global source (rule 21)
#pragma unroll
    for (int i = 0; i < 4; ++i) {
      int row = i * 32 + row_s;
      int grp = grp_s ^ (row & 7);
      gld_lds16(A + (size_t)(m0 + row) * K + kt + grp * 8, sA + i * 2048 + wid * 512);
      gld_lds16(Bt + (size_t)(n0 + row) * K + kt + grp * 8, sB + i * 2048 + wid * 512);
    }
    __syncthreads();
#pragma unroll
    for (int ks = 0; ks < 2; ++ks) {
      short8 af[4], bf[4];
#pragma unroll
      for (int i = 0; i < 4; ++i) {
        int rA = wr + i * 16 + lr;
        af[i] = lds8(sA, rA * 128 + (((ks * 4 + lg) ^ (rA & 7)) << 4));
        int rB = wc + i * 16 + lr;
        bf[i] = lds8(sB, rB * 128 + (((ks * 4 + lg) ^ (rB & 7)) << 4));
      }
#pragma unroll
      for (int i = 0; i < 4; ++i)
#pragma unroll
        for (int j = 0; j < 4; ++j)
          acc[i][j] = __builtin_amdgcn_mfma_f32_16x16x32_bf16(af[i], bf[j], acc[i][j], 0, 0, 0);
    }
    __syncthreads();
  }

  // epilogue: C row = (lane>>4)*4 + reg, col = lane&15 (m89/m91 layout)
#pragma unroll
  for (int i = 0; i < 4; ++i) {
#pragma unroll
    for (int j = 0; j < 4; ++j) {
#pragma unroll
      for (int r = 0; r < 4; ++r) {
        int row = m0 + wr + i * 16 + lg * 4 + r;
        int col = n0 + wc + j * 16 + lr;
        float v = acc[i][j][r] + bias[col];
        if (EPI == 0) {
          int which = col >> 10;
          int h = (col >> 6) & 15;
          int d = col & 63;
          int b = row >> 11;
          int s = row & 2047;
          size_t idx = ((size_t)(b * 16 + h) * 2048 + s) * 64 + d;
          bfbits bv = f2bf(v);
          if (which == 0) outQ[idx] = bv;
          else if (which == 1) outK[idx] = bv;
          else outV[idx] = bv;
        } else {
          outF[(size_t)row * N + col] = v;
        }
      }
    }
  }
}

// ---------------- flash attention: Q,K,V [BH][S][HD] bf16 -> O [B][S][H*HD] bf16 ----------------
__global__ __launch_bounds__(256, 2) void attn_kernel(
    const bfbits* __restrict__ Q, const bfbits* __restrict__ K,
    const bfbits* __restrict__ V, bfbits* __restrict__ O) {
  __shared__ bfbits sK[64 * 64];     // [kv][d], swizzled
  __shared__ bfbits sV[64 * 64];     // [d][kv], swizzled (transposed)
  __shared__ bfbits sP[4][32 * 64];  // per-wave P, swizzled

  const int t = threadIdx.x, wid = t >> 6, l = t & 63;
  const int lr = l & 15, lg = l >> 4;
  const int bh = blockIdx.y;
  const int b = bh >> 4, h = bh & 15;
  const int q0 = blockIdx.x * 128;

  const bfbits* Qb = Q + (size_t)bh * Sc * HDc;
  const bfbits* Kb = K + (size_t)bh * Sc * HDc;
  const bfbits* Vb = V + (size_t)bh * Sc * HDc;

  // Q fragments hoisted to registers: rows q0+wid*32+rt*16+lr, k = ks*32+lg*8
  short8 qf[2][2];
#pragma unroll
  for (int rt = 0; rt < 2; ++rt)
#pragma unroll
    for (int ks = 0; ks < 2; ++ks)
      qf[rt][ks] = *(const short8*)(Qb + (size_t)(q0 + wid * 32 + rt * 16 + lr) * 64 + ks * 32 + lg * 8);

  f32x4 acc[2][4];
  float mrow[2][4], lpart[2][4];
#pragma unroll
  for (int rt = 0; rt < 2; ++rt) {
#pragma unroll
    for (int dt = 0; dt < 4; ++dt) acc[rt][dt] = zero4();
#pragma unroll
    for (int r = 0; r < 4; ++r) { mrow[rt][r] = -1e30f; lpart[rt][r] = 0.f; }
  }

  const float cscale = 0.125f * 1.4426950408889634f; // rsqrt(HD) * log2(e)

  const int nkv = (q0 + 128) >> 6;
  const int row_s = t >> 3, grp_s = t & 7;

  for (int kb = 0; kb < nkv; ++kb) {
    const int kv0 = kb * 64;
    // stage K [64][64] via global_load_lds, source pre-swizzled
#pragma unroll
    for (int i = 0; i < 2; ++i) {
      int row = i * 32 + row_s;
      int grp = grp_s ^ (row & 7);
      gld_lds16(Kb + (size_t)(kv0 + row) * 64 + grp * 8, sK + i * 2048 + wid * 512);
    }
    // stage V transposed (reg-staged), swizzled writes
#pragma unroll
    for (int i = 0; i < 2; ++i) {
      int kv = i * 32 + row_s;
      short8 v = *(const short8*)(Vb + (size_t)(kv0 + kv) * 64 + grp_s * 8);
#pragma unroll
      for (int j = 0; j < 8; ++j) {
        int d = grp_s * 8 + j;
        int byteo = d * 128 + ((((kv >> 3) ^ (d & 7))) << 4) + (kv & 7) * 2;
        *(short*)((char*)sV + byteo) = v[j];
      }
    }
    __syncthreads();

    // QK^T scores: A=Q, B=K (col = kv)
    f32x4 sc[2][4];
#pragma unroll
    for (int rt = 0; rt < 2; ++rt)
#pragma unroll
      for (int ktile = 0; ktile < 4; ++ktile) sc[rt][ktile] = zero4();
#pragma unroll
    for (int ks = 0; ks < 2; ++ks) {
#pragma unroll
      for (int ktile = 0; ktile < 4; ++ktile) {
        int rK = ktile * 16 + lr;
        short8 kf = lds8(sK, rK * 128 + (((ks * 4 + lg) ^ (rK & 7)) << 4));
#pragma unroll
        for (int rt = 0; rt < 2; ++rt)
          sc[rt][ktile] = __builtin_amdgcn_mfma_f32_16x16x32_bf16(qf[rt][ks], kf, sc[rt][ktile], 0, 0, 0);
      }
    }

    // scale + causal mask (wave-uniform edge test)
    const bool edge = (kv0 + 63) > (q0 + wid * 32);
#pragma unroll
    for (int rt = 0; rt < 2; ++rt)
#pragma unroll
      for (int ktile = 0; ktile < 4; ++ktile)
#pragma unroll
        for (int r = 0; r < 4; ++r) {
          float sval = sc[rt][ktile][r] * cscale;
          if (edge) {
            int qa = q0 + wid * 32 + rt * 16 + lg * 4 + r;
            int ka = kv0 + ktile * 16 + lr;
            if (ka > qa) sval = -1e30f;
          }
          sc[rt][ktile][r] = sval;
        }

    // online softmax (exp2 domain), row = lg*4+r, spread over 16 lanes (kv cols)
#pragma unroll
    for (int rt = 0; rt < 2; ++rt) {
#pragma unroll
      for (int r = 0; r < 4; ++r) {
        float mx = fmaxf(fmaxf(sc[rt][0][r], sc[rt][1][r]), fmaxf(sc[rt][2][r], sc[rt][3][r]));
#pragma unroll
        for (int o = 1; o < 16; o <<= 1) mx = fmaxf(mx, __shfl_xor(mx, o));
        float mnew = fmaxf(mrow[rt][r], mx);
        float sold = exp2f(mrow[rt][r] - mnew);
        mrow[rt][r] = mnew;
        float ssum = 0.f;
#pragma unroll
        for (int ktile = 0; ktile < 4; ++ktile) {
          float p = exp2f(sc[rt][ktile][r] - mnew);
          sc[rt][ktile][r] = p;
          ssum += p;
        }
        lpart[rt][r] = lpart[rt][r] * sold + ssum;
#pragma unroll
        for (int dt = 0; dt < 4; ++dt) acc[rt][dt][r] *= sold;
      }
    }

    // write P to per-wave LDS (swizzled), then PV
    bfbits* Pw = sP[wid];
#pragma unroll
    for (int rt = 0; rt < 2; ++rt)
#pragma unroll
      for (int ktile = 0; ktile < 4; ++ktile)
#pragma unroll
        for (int r = 0; r < 4; ++r) {
          int row = rt * 16 + lg * 4 + r;
          int col = ktile * 16 + lr;
          int byteo = row * 128 + ((((col >> 3) ^ (row & 7))) << 4) + (col & 7) * 2;
          *(short*)((char*)Pw + byteo) = (short)f2bf(sc[rt][ktile][r]);
        }

    // PV: A = P (rows q, k = kv), B = V^T-staged (col = d, k = kv)
#pragma unroll
    for (int ks = 0; ks < 2; ++ks) {
      short8 pf[2];
#pragma unroll
      for (int rt = 0; rt < 2; ++rt) {
        int rp = rt * 16 + lr;
        pf[rt] = lds8(Pw, rp * 128 + (((ks * 4 + lg) ^ (rp & 7)) << 4));
      }
#pragma unroll
      for (int dt = 0; dt < 4; ++dt) {
        int rv = dt * 16 + lr;
        short8 vf = lds8(sV, rv * 128 + (((ks * 4 + lg) ^ (rv & 7)) << 4));
#pragma unroll
        for (int rt = 0; rt < 2; ++rt)
          acc[rt][dt] = __builtin_amdgcn_mfma_f32_16x16x32_bf16(pf[rt], vf, acc[rt][dt], 0, 0, 0);
      }
    }
    __syncthreads();
  }

  // finalize: reduce lpart across the 16 kv-lanes, normalize, store O [B][S][H*HD]
#pragma unroll
  for (int rt = 0; rt < 2; ++rt) {
#pragma unroll
    for (int r = 0; r < 4; ++r) {
      float lsum = lpart[rt][r];
#pragma unroll
      for (int o = 1; o < 16; o <<= 1) lsum += __shfl_xor(lsum, o);
      float inv = 1.0f / lsum;
      int srow = q0 + wid * 32 + rt * 16 + lg * 4 + r;
#pragma unroll
      for (int dt = 0; dt < 4; ++dt) {
        int d = dt * 16 + lr;
        O[((size_t)(b * Sc + srow) * Hc + h) * HDc + d] = f2bf(acc[rt][dt][r] * inv);
      }
    }
  }
}

// ---------------- launch ----------------
extern "C" void kernel_launch(void* const* d_in, const int* in_sizes, int n_in,
                              void* d_out, int out_size, void* d_ws, size_t ws_size,
                              hipStream_t stream) {
  const float* x = (const float*)d_in[0];
  const float* w_qkv = (const float*)d_in[1];
  const float* b_qkv = (const float*)d_in[2];
  const float* w_proj = (const float*)d_in[3];
  const float* b_proj = (const float*)d_in[4];
  float* out = (float*)d_out;

  char* ws = (char*)d_ws;
  size_t off = 0;
  auto alloc = [&](size_t bytes) {
    char* p = ws + off;
    off = off + ((bytes + 255) & ~(size_t)255);
    return p;
  };
  bfbits* Xb = (bfbits*)alloc((size_t)M1 * Kd * 2);          // 16.8 MB
  bfbits* WqkvT = (bfbits*)alloc((size_t)N1 * Kd * 2);       // 6.3 MB
  bfbits* WprojT = (bfbits*)alloc((size_t)Dc * Dc * 2);      // 2.1 MB
  bfbits* Qb = (bfbits*)alloc((size_t)Bc * Hc * Sc * HDc * 2);
  bfbits* Kb = (bfbits*)alloc((size_t)Bc * Hc * Sc * HDc * 2);
  bfbits* Vb = (bfbits*)alloc((size_t)Bc * Hc * Sc * HDc * 2);
  bfbits* Ob = Xb; // alias: Xb dead after GEMM1

  cast_x_kernel<<<(M1 * Kd / 8 + 255) / 256, 256, 0, stream>>>(x, Xb, M1 * Kd / 8);
  transpose_cast_kernel<<<dim3(N1 / 32, Kd / 32), 256, 0, stream>>>(w_qkv, WqkvT, Kd, N1);
  transpose_cast_kernel<<<dim3(Dc / 32, Dc / 32), 256, 0, stream>>>(w_proj, WprojT, Dc, Dc);

  gemm_bt_kernel<0><<<dim3(N1 / 128, M1 / 128), 256, 0, stream>>>(
      Xb, WqkvT, b_qkv, Qb, Kb, Vb, nullptr, M1, N1, Kd);

  attn_kernel<<<dim3(Sc / 128, Bc * Hc), 256, 0, stream>>>(Qb, Kb, Vb, Ob);

  gemm_bt_kernel<1><<<dim3(Dc / 128, M1 / 128), 256, 0, stream>>>(
      Ob, WprojT, b_proj, nullptr, nullptr, nullptr, out, M1, Dc, Kd);
}

// Round 5
// 271.730 us; speedup vs baseline: 1.5592x; 1.5592x over previous
//
#include <hip/hip_runtime.h>

typedef __attribute__((ext_vector_type(8))) short short8;
typedef __attribute__((ext_vector_type(4))) float f32x4;
typedef __attribute__((ext_vector_type(16))) float f32x16;
typedef __attribute__((ext_vector_type(4))) float flt4;
typedef __attribute__((ext_vector_type(4))) unsigned int u32x4;
typedef unsigned short bfbits;

#define DEVI __device__ __forceinline__

constexpr int Bc = 4, Sc = 2048, Dc = 1024, Hc = 16, HDc = 64;
constexpr int M1 = Bc * Sc;      // 8192
constexpr int N1 = 3 * Hc * HDc; // 3072
constexpr int Kd = Dc;           // 1024

typedef __attribute__((address_space(1))) const unsigned int gas_u32;
typedef __attribute__((address_space(3))) unsigned int las_u32;

DEVI void gld_lds16(const void* g, void* l) {
  __builtin_amdgcn_global_load_lds((gas_u32*)g, (las_u32*)l, 16, 0, 0);
}

DEVI unsigned short f2bf(float f) {
  unsigned int x = __builtin_bit_cast(unsigned int, f);
  x = x + 0x7fffu + ((x >> 16) & 1u);
  return (unsigned short)(x >> 16);
}

DEVI f32x4 zero4() { f32x4 z = {0.f, 0.f, 0.f, 0.f}; return z; }

DEVI short8 lds8(const void* base, int byteoff) {
  return *(const short8*)((const char*)base + byteoff);
}

DEVI unsigned int cvtpk_bf16(float lo, float hi) {
  unsigned int r;
  asm("v_cvt_pk_bf16_f32 %0, %1, %2" : "=v"(r) : "v"(lo), "v"(hi));
  return r;
}

// v_permlane32_swap_b32 vdst, vsrc: new_dst.hi = old_src.lo; new_src.lo = old_dst.hi
// ("odd 32-lane row of vdst" <-> "even 32-lane row of vsrc")
DEVI void pl32swap(unsigned int& dst, unsigned int& src) {
  asm volatile("v_permlane32_swap_b32 %0, %1" : "+v"(dst), "+v"(src));
}

// ---------------- cast x (fp32 -> bf16), 8 elems/thread ----------------
__global__ void cast_x_kernel(const float* __restrict__ in, bfbits* __restrict__ out, int n8) {
  int i = blockIdx.x * 256 + threadIdx.x;
  if (i >= n8) return;
  const flt4* p = (const flt4*)in;
  flt4 a = p[(size_t)2 * i];
  flt4 b = p[(size_t)2 * i + 1];
  short8 r;
  r[0] = (short)f2bf(a[0]); r[1] = (short)f2bf(a[1]);
  r[2] = (short)f2bf(a[2]); r[3] = (short)f2bf(a[3]);
  r[4] = (short)f2bf(b[0]); r[5] = (short)f2bf(b[1]);
  r[6] = (short)f2bf(b[2]); r[7] = (short)f2bf(b[3]);
  *(short8*)(out + (size_t)8 * i) = r;
}

// ---------------- transpose + cast: in[R][C] fp32 -> out[C][R] bf16 ----------------
__global__ void transpose_cast_kernel(const float* __restrict__ in, bfbits* __restrict__ out,
                                      int R, int C) {
  __shared__ float tile[32][33];
  int bc = blockIdx.x * 32, br = blockIdx.y * 32;
  int tx = threadIdx.x & 31, ty = threadIdx.x >> 5; // 32 x 8
#pragma unroll
  for (int i = 0; i < 32; i += 8)
    tile[ty + i][tx] = in[(size_t)(br + ty + i) * C + bc + tx];
  __syncthreads();
#pragma unroll
  for (int i = 0; i < 32; i += 8)
    out[(size_t)(bc + ty + i) * R + br + tx] = f2bf(tile[tx][ty + i]);
}

// ---------------- GEMM: C[M][N] = A[M][K] * Bt[N][K]^T + bias ----------------
// EPI 0: scatter bf16 into Q/K [BH][S][HD] and V TRANSPOSED [BH][HD][S]
// EPI 1: fp32 out[M][N]
template <int EPI>
__global__ __launch_bounds__(256, 2) void gemm_bt_kernel(
    const bfbits* __restrict__ A, const bfbits* __restrict__ Bt,
    const float* __restrict__ bias,
    bfbits* __restrict__ outQ, bfbits* __restrict__ outK, bfbits* __restrict__ outV,
    float* __restrict__ outF, int M, int N, int K) {
  __shared__ bfbits sA[128 * 64];
  __shared__ bfbits sB[128 * 64];
  const int t = threadIdx.x;
  const int wid = t >> 6, l = t & 63;
  const int lr = l & 15, lg = l >> 4;
  const int m0 = blockIdx.y * 128, n0 = blockIdx.x * 128;
  const int wr = (wid >> 1) * 64, wc = (wid & 1) * 64;

  f32x4 acc[4][4];
#pragma unroll
  for (int i = 0; i < 4; ++i)
#pragma unroll
    for (int j = 0; j < 4; ++j) acc[i][j] = zero4();

  const int row_s = t >> 3; // 0..31
  const int grp_s = t & 7;

  for (int kt = 0; kt < K; kt += 64) {
#pragma unroll
    for (int i = 0; i < 4; ++i) {
      int row = i * 32 + row_s;
      int grp = grp_s ^ (row & 7);
      gld_lds16(A + (size_t)(m0 + row) * K + kt + grp * 8, sA + i * 2048 + wid * 512);
      gld_lds16(Bt + (size_t)(n0 + row) * K + kt + grp * 8, sB + i * 2048 + wid * 512);
    }
    __syncthreads();
#pragma unroll
    for (int ks = 0; ks < 2; ++ks) {
      short8 af[4], bf[4];
#pragma unroll
      for (int i = 0; i < 4; ++i) {
        int rA = wr + i * 16 + lr;
        af[i] = lds8(sA, rA * 128 + (((ks * 4 + lg) ^ (rA & 7)) << 4));
        int rB = wc + i * 16 + lr;
        bf[i] = lds8(sB, rB * 128 + (((ks * 4 + lg) ^ (rB & 7)) << 4));
      }
#pragma unroll
      for (int i = 0; i < 4; ++i)
#pragma unroll
        for (int j = 0; j < 4; ++j)
          acc[i][j] = __builtin_amdgcn_mfma_f32_16x16x32_bf16(af[i], bf[j], acc[i][j], 0, 0, 0);
    }
    __syncthreads();
  }

#pragma unroll
  for (int i = 0; i < 4; ++i) {
#pragma unroll
    for (int j = 0; j < 4; ++j) {
#pragma unroll
      for (int r = 0; r < 4; ++r) {
        int row = m0 + wr + i * 16 + lg * 4 + r;
        int col = n0 + wc + j * 16 + lr;
        float v = acc[i][j][r] + bias[col];
        if (EPI == 0) {
          int which = col >> 10;
          int h = (col >> 6) & 15;
          int d = col & 63;
          int b = row >> 11;
          int s = row & 2047;
          bfbits bv = f2bf(v);
          if (which == 0) {
            outQ[((size_t)(b * 16 + h) * 2048 + s) * 64 + d] = bv;
          } else if (which == 1) {
            outK[((size_t)(b * 16 + h) * 2048 + s) * 64 + d] = bv;
          } else {
            // V transposed: [bh][d][s]
            outV[((size_t)(b * 16 + h) * 64 + d) * 2048 + s] = bv;
          }
        } else {
          outF[(size_t)row * N + col] = v;
        }
      }
    }
  }
}

// ---------------- flash attention: 32x32 MFMA, in-register softmax ----------------
// Q,K [BH][S][HD] bf16; Vt [BH][HD][S] bf16 -> O [B][S][H*HD] bf16
// Block: 4 waves x 32 q-rows = 128-row q-tile; two tiles (pr, 15-pr) per block.
// S^T = mfma(K_frag, Q_frag): lane holds q = l&31, kv = (r&3)+8*(r>>2)+4*(l>>5).
__global__ __launch_bounds__(256, 2) void attn_kernel(
    const bfbits* __restrict__ Q, const bfbits* __restrict__ K,
    const bfbits* __restrict__ Vt, bfbits* __restrict__ O) {
  __shared__ bfbits sK[64 * 64]; // [kv][d], swizzled 16B groups
  __shared__ bfbits sV[64 * 64]; // [d][kv], swizzled 16B groups

  const int t = threadIdx.x, wid = t >> 6, l = t & 63;
  const int lq = l & 31, b5 = l >> 5;

  const int id = blockIdx.x; // 0..511
  const int swz = (id & 7) * 64 + (id >> 3);
  const int pr = swz & 7;
  const int bh = swz >> 3;
  const int b = bh >> 4, h = bh & 15;

  const bfbits* Qb = Q + (size_t)bh * Sc * HDc;
  const bfbits* Kb = K + (size_t)bh * Sc * HDc;
  const bfbits* Vtb = Vt + (size_t)bh * Sc * HDc;

  const float cscale = 0.125f * 1.4426950408889634f; // rsqrt(HD) * log2(e)
  const int row_s = t >> 3, grp_s = t & 7;

  for (int half = 0; half < 2; ++half) {
    const int qt = half ? (15 - pr) : pr;
    const int qb = qt * 128;
    const int qrow = qb + wid * 32 + lq;
    const int qmaxw = qb + wid * 32 + 31;

    // Q frags (B-operand): lane holds Q[qrow][d = ds*16 + b5*8 + j]
    short8 qf[4];
#pragma unroll
    for (int ds = 0; ds < 4; ++ds)
      qf[ds] = *(const short8*)(Qb + (size_t)qrow * 64 + ds * 16 + b5 * 8);

    f32x16 acc0 = {0.f, 0.f, 0.f, 0.f, 0.f, 0.f, 0.f, 0.f,
                   0.f, 0.f, 0.f, 0.f, 0.f, 0.f, 0.f, 0.f};
    f32x16 acc1 = acc0;
    float mrow = 0.f, lrow = 0.f; // defer-max: m starts at 0, THR=8 in exp2 domain

    const int nkv = 2 * (qt + 1);
    for (int kb = 0; kb < nkv; ++kb) {
      const int kv0 = kb * 64;
      // stage K rows (kv) and Vt rows (d) via global_load_lds, source pre-swizzled
#pragma unroll
      for (int i = 0; i < 2; ++i) {
        int rr = i * 32 + row_s;
        int grp = grp_s ^ (rr & 7);
        gld_lds16(Kb + (size_t)(kv0 + rr) * 64 + grp * 8, sK + i * 2048 + wid * 512);
        gld_lds16(Vtb + (size_t)rr * Sc + kv0 + grp * 8, sV + i * 2048 + wid * 512);
      }
      __syncthreads();

      if (kv0 <= qmaxw) {
#pragma unroll
        for (int sub = 0; sub < 2; ++sub) {
          const int kvb = kv0 + sub * 32;
          if (kvb <= qmaxw) {
            // S^T = K . Q^T over d (4 k-steps of 16)
            f32x16 st = {0.f, 0.f, 0.f, 0.f, 0.f, 0.f, 0.f, 0.f,
                         0.f, 0.f, 0.f, 0.f, 0.f, 0.f, 0.f, 0.f};
            const int rK = sub * 32 + lq;
            const int swK = rK & 7;
#pragma unroll
            for (int ds = 0; ds < 4; ++ds) {
              short8 kf = lds8(sK, rK * 128 + (((ds * 2 + b5) ^ swK) << 4));
              st = __builtin_amdgcn_mfma_f32_32x32x16_bf16(kf, qf[ds], st, 0, 0, 0);
            }
            // scale + causal mask (diagonal sub-tiles are 32-aligned with q rows)
            if (kvb + 31 > qb + wid * 32) {
#pragma unroll
              for (int r = 0; r < 16; ++r) {
                int kvi = kvb + (r & 3) + 8 * (r >> 2) + 4 * b5;
                st[r] = (kvi > qrow) ? -1e30f : st[r] * cscale;
              }
            } else {
#pragma unroll
              for (int r = 0; r < 16; ++r) st[r] *= cscale;
            }
            // tile max (in-reg + 1 shfl); defer-max rescale
            float mx = st[0];
#pragma unroll
            for (int r = 1; r < 16; ++r) mx = fmaxf(mx, st[r]);
            mx = fmaxf(mx, __shfl_xor(mx, 32));
            if (__any(mx > mrow + 8.f)) {
              float mnew = fmaxf(mrow, mx);
              float sold = exp2f(mrow - mnew);
              mrow = mnew;
              lrow *= sold;
#pragma unroll
              for (int r = 0; r < 16; ++r) {
                float sb = __shfl(sold, (r & 3) + 8 * (r >> 2) + 4 * b5, 32);
                acc0[r] *= sb;
                acc1[r] *= sb;
              }
            }
            // P = exp2(st - m), row-sum into lrow
            float ssum = 0.f;
#pragma unroll
            for (int r = 0; r < 16; ++r) {
              float p = exp2f(st[r] - mrow);
              st[r] = p;
              ssum += p;
            }
            lrow += ssum;
            // P relayout: cvt_pk + permlane32_swap (crosses only lane bit 5).
            // Semantics: swap(dst, src): dst.hi <- src.lo, src.lo <- dst.hi.
            unsigned int W0 = cvtpk_bf16(st[0], st[1]);
            unsigned int W1 = cvtpk_bf16(st[2], st[3]);
            unsigned int W2 = cvtpk_bf16(st[4], st[5]);
            unsigned int W3 = cvtpk_bf16(st[6], st[7]);
            unsigned int W4 = cvtpk_bf16(st[8], st[9]);
            unsigned int W5 = cvtpk_bf16(st[10], st[11]);
            unsigned int W6 = cvtpk_bf16(st[12], st[13]);
            unsigned int W7 = cvtpk_bf16(st[14], st[15]);
            pl32swap(W0, W2); // W0 = {W0.lo, W2.lo} = pa0 slot0; W2 = {W0.hi, W2.hi} = slot2
            pl32swap(W1, W3); // W1 -> pa0 slot1; W3 -> pa0 slot3
            pl32swap(W4, W6); // W4 -> pa1 slot0; W6 -> pa1 slot2
            pl32swap(W5, W7); // W5 -> pa1 slot1; W7 -> pa1 slot3
            u32x4 pa0u = {W0, W1, W2, W3};
            u32x4 pa1u = {W4, W5, W6, W7};
            short8 pa0 = __builtin_bit_cast(short8, pa0u);
            short8 pa1 = __builtin_bit_cast(short8, pa1u);
            // PV: A = P[q][kv16], B = V^T (lane holds V[kv][d=dt*32+lq])
#pragma unroll
            for (int dt = 0; dt < 2; ++dt) {
              int rv = dt * 32 + lq;
              int swV = rv & 7;
              short8 vf0 = lds8(sV, rv * 128 + (((sub * 4 + 0 + b5) ^ swV) << 4));
              short8 vf1 = lds8(sV, rv * 128 + (((sub * 4 + 2 + b5) ^ swV) << 4));
              if (dt == 0) {
                acc0 = __builtin_amdgcn_mfma_f32_32x32x16_bf16(pa0, vf0, acc0, 0, 0, 0);
                acc0 = __builtin_amdgcn_mfma_f32_32x32x16_bf16(pa1, vf1, acc0, 0, 0, 0);
              } else {
                acc1 = __builtin_amdgcn_mfma_f32_32x32x16_bf16(pa0, vf0, acc1, 0, 0, 0);
                acc1 = __builtin_amdgcn_mfma_f32_32x32x16_bf16(pa1, vf1, acc1, 0, 0, 0);
              }
            }
          }
        }
      }
      __syncthreads();
    }

    // finalize: combine the two lane-halves' partial sums, normalize, store
    float lsum = lrow + __shfl_xor(lrow, 32);
    float inv = 1.0f / lsum;
#pragma unroll
    for (int r = 0; r < 16; ++r) {
      int qrel = (r & 3) + 8 * (r >> 2) + 4 * b5;
      float ib = __shfl(inv, qrel, 32);
      int srow = qb + wid * 32 + qrel;
      size_t base = (size_t)(b * Sc + srow) * (Hc * HDc) + h * 64;
      O[base + lq] = f2bf(acc0[r] * ib);
      O[base + 32 + lq] = f2bf(acc1[r] * ib);
    }
  }
}

// ---------------- launch ----------------
extern "C" void kernel_launch(void* const* d_in, const int* in_sizes, int n_in,
                              void* d_out, int out_size, void* d_ws, size_t ws_size,
                              hipStream_t stream) {
  const float* x = (const float*)d_in[0];
  const float* w_qkv = (const float*)d_in[1];
  const float* b_qkv = (const float*)d_in[2];
  const float* w_proj = (const float*)d_in[3];
  const float* b_proj = (const float*)d_in[4];
  float* out = (float*)d_out;

  char* ws = (char*)d_ws;
  size_t off = 0;
  auto alloc = [&](size_t bytes) {
    char* p = ws + off;
    off = off + ((bytes + 255) & ~(size_t)255);
    return p;
  };
  bfbits* Xb = (bfbits*)alloc((size_t)M1 * Kd * 2);
  bfbits* WqkvT = (bfbits*)alloc((size_t)N1 * Kd * 2);
  bfbits* WprojT = (bfbits*)alloc((size_t)Dc * Dc * 2);
  bfbits* Qb = (bfbits*)alloc((size_t)Bc * Hc * Sc * HDc * 2);
  bfbits* Kb = (bfbits*)alloc((size_t)Bc * Hc * Sc * HDc * 2);
  bfbits* Vtb = (bfbits*)alloc((size_t)Bc * Hc * Sc * HDc * 2);
  bfbits* Ob = Xb; // alias: Xb dead after GEMM1

  cast_x_kernel<<<(M1 * Kd / 8 + 255) / 256, 256, 0, stream>>>(x, Xb, M1 * Kd / 8);
  transpose_cast_kernel<<<dim3(N1 / 32, Kd / 32), 256, 0, stream>>>(w_qkv, WqkvT, Kd, N1);
  transpose_cast_kernel<<<dim3(Dc / 32, Dc / 32), 256, 0, stream>>>(w_proj, WprojT, Dc, Dc);

  gemm_bt_kernel<0><<<dim3(N1 / 128, M1 / 128), 256, 0, stream>>>(
      Xb, WqkvT, b_qkv, Qb, Kb, Vtb, nullptr, M1, N1, Kd);

  attn_kernel<<<dim3(512), 256, 0, stream>>>(Qb, Kb, Vtb, Ob);

  gemm_bt_kernel<1><<<dim3(Dc / 128, M1 / 128), 256, 0, stream>>>(
      Ob, WprojT, b_proj, nullptr, nullptr, nullptr, out, M1, Dc, Kd);
}